// Round 4
// baseline (29.502 us; speedup 1.0000x reference)
//
#include <hip/hip_runtime.h>

// out[b, i] = prod_{d=0..7} in[b, digit_d(i), d],  i = sum digit_d * 4^(7-d)
// Fully factored form: i = (q, v-bits, t-bits, i7) ->
//   out = x0[q] * x1[v>>2] * x2[v&3] * x3[t>>6] * x4[(t>>4)&3]
//         * x5[(t>>2)&3] * x6[t&3] * x7[i7]
// No LDS, no barriers: block-uniform factors become scalar loads, per-lane
// factors are 4 tiny L1-resident loads. 16 nontemporal float4 stores/thread.

typedef float floatx4 __attribute__((ext_vector_type(4)));

__global__ __launch_bounds__(256) void rule_outer_kernel(
    const float* __restrict__ in, float* __restrict__ out) {
    const int bb = blockIdx.x;
    const int b = bb >> 2;       // batch element
    const int q = bb & 3;        // quarter of the 65536-wide output row
    const int t = threadIdx.x;

    const float* xb = in + b * 32;  // xb[m*8 + d]

    // Per-lane constant product: x3[t>>6] * x4[(t>>4)&3] * x5[(t>>2)&3] * x6[t&3]
    const float p36 = xb[((t >> 6) & 3) * 8 + 3] * xb[((t >> 4) & 3) * 8 + 4] *
                      xb[((t >> 2) & 3) * 8 + 5] * xb[(t & 3) * 8 + 6];
    // Block-uniform leading digit
    const float base = xb[q * 8 + 0] * p36;
    // Innermost digit vector: x7[0..3]
    floatx4 tf;
    tf.x = base * xb[0 * 8 + 7];
    tf.y = base * xb[1 * 8 + 7];
    tf.z = base * xb[2 * 8 + 7];
    tf.w = base * xb[3 * 8 + 7];

    floatx4* outv = reinterpret_cast<floatx4*>(out) + (size_t)b * 16384 + q * 4096;

#pragma unroll
    for (int v = 0; v < 16; ++v) {
        // Block-uniform per-v factor (scalar ops): x1[v>>2] * x2[v&3]
        const float h12 = xb[(v >> 2) * 8 + 1] * xb[(v & 3) * 8 + 2];
        const floatx4 o = h12 * tf;
        __builtin_nontemporal_store(o, &outv[v * 256 + t]);
    }
}

extern "C" void kernel_launch(void* const* d_in, const int* in_sizes, int n_in,
                              void* d_out, int out_size, void* d_ws, size_t ws_size,
                              hipStream_t stream) {
    const float* in = (const float*)d_in[0];
    float* out = (float*)d_out;
    const int B = in_sizes[0] / 32;  // B*M*D = B*32
    rule_outer_kernel<<<B * 4, 256, 0, stream>>>(in, out);
}

// Round 5
// 25.563 us; speedup vs baseline: 1.1541x; 1.1541x over previous
//
#include <hip/hip_runtime.h>

// out[b, i] = prod_{d=0..7} in[b, digit_d(i), d],  i = sum digit_d * 4^(7-d)
// Fully factored form: i = (q, v-bits, t-bits, i7) ->
//   out = x0[q] * x1[v>>2] * x2[v&3] * x3[t>>6] * x4[(t>>4)&3]
//         * x5[(t>>2)&3] * x6[t&3] * x7[i7]
// No LDS, no barriers. Plain (cached) float4 stores — nontemporal regressed
// (29.5 vs 25.7 µs): nt bypasses the L2 write path the fill kernel uses.

typedef float floatx4 __attribute__((ext_vector_type(4)));

__global__ __launch_bounds__(256) void rule_outer_kernel(
    const float* __restrict__ in, float* __restrict__ out) {
    const int bb = blockIdx.x;
    const int b = bb >> 2;       // batch element
    const int q = bb & 3;        // quarter of the 65536-wide output row
    const int t = threadIdx.x;

    const float* xb = in + b * 32;  // xb[m*8 + d]

    // Per-lane constant product: x3[t>>6] * x4[(t>>4)&3] * x5[(t>>2)&3] * x6[t&3]
    const float p36 = xb[((t >> 6) & 3) * 8 + 3] * xb[((t >> 4) & 3) * 8 + 4] *
                      xb[((t >> 2) & 3) * 8 + 5] * xb[(t & 3) * 8 + 6];
    // Block-uniform leading digit
    const float base = xb[q * 8 + 0] * p36;
    // Innermost digit vector: x7[0..3]
    floatx4 tf;
    tf.x = base * xb[0 * 8 + 7];
    tf.y = base * xb[1 * 8 + 7];
    tf.z = base * xb[2 * 8 + 7];
    tf.w = base * xb[3 * 8 + 7];

    floatx4* outv = reinterpret_cast<floatx4*>(out) + (size_t)b * 16384 + q * 4096;

#pragma unroll
    for (int v = 0; v < 16; ++v) {
        // Block-uniform per-v factor (scalar ops): x1[v>>2] * x2[v&3]
        const float h12 = xb[(v >> 2) * 8 + 1] * xb[(v & 3) * 8 + 2];
        outv[v * 256 + t] = h12 * tf;
    }
}

extern "C" void kernel_launch(void* const* d_in, const int* in_sizes, int n_in,
                              void* d_out, int out_size, void* d_ws, size_t ws_size,
                              hipStream_t stream) {
    const float* in = (const float*)d_in[0];
    float* out = (float*)d_out;
    const int B = in_sizes[0] / 32;  // B*M*D = B*32
    rule_outer_kernel<<<B * 4, 256, 0, stream>>>(in, out);
}